// Round 18
// baseline (243.670 us; speedup 1.0000x reference)
//
#include <hip/hip_runtime.h>
#include <hip/hip_bf16.h>
#include <math.h>

#define NNODES 50000
#define NEDGES 600000
#define FDIM   128
#define NCLS   40
#define SLOTS  64                        // static CSR slots per node (start = node*64)
#define FILL_BLOCKS 1172                 // 2 edges/thread: 1172*512 >= 600000
#define CVT_BLOCKS 6250                  // 50000*128/4/256 exact
#define R1_BLOCKS 3125                   // x @ Wr1 + bl1 precompute (16 rows/block)
#define ALL_TOTAL (FILL_BLOCKS + CVT_BLOCKS + R1_BLOCKS)
#define CZ_BLOCKS 49                     // cursor zero (12544*4 ints >= 50000)
#define PRE_TOTAL (CZ_BLOCKS + 62)       // + pack/bias
#define NT16 (NNODES / 16)               // 3125 four-wave tiles of 16 rows (exact)

typedef __hip_bfloat16 bf16;
typedef short bf16x8 __attribute__((ext_vector_type(8)));
typedef short bf16x4 __attribute__((ext_vector_type(4)));
typedef float f32x4  __attribute__((ext_vector_type(4)));
typedef float f32x2  __attribute__((ext_vector_type(2)));
typedef unsigned u32x4 __attribute__((ext_vector_type(4)));

__device__ __forceinline__ float u2f(unsigned u) {
    union { unsigned i; float f; } cv;
    cv.i = u;
    return cv.f;
}
__device__ __forceinline__ short f2b(float f) {
    bf16 h = __float2bfloat16(f);
    return *(const short*)&h;
}
__device__ __forceinline__ float ldf(const void* p, int fp32, int idx) {
    return fp32 ? ((const float*)p)[idx]
                : __bfloat162float(((const bf16*)p)[idx]);
}
// Per-wave float-dtype detection from 64 samples of the array's first words.
__device__ __forceinline__ int wave_is_fp32(const unsigned* p, int lane) {
    unsigned w = p[lane];
    unsigned e = (w >> 7) & 0xFFu;
    int inr = (e >= 100u && e <= 140u) ? 1 : 0;
    return (int)__popcll(__ballot(inr)) < 32;
}
// LDS addressing: flat 128-short rows, 8-short chunks XOR-swizzled by row&15.
// [verified r9-r17: SQ_LDS_BANK_CONFLICT = 0]
__device__ __forceinline__ int lidx(int row, int col) {
    return row * 128 + ((((col >> 3) ^ (row & 15)) << 3) | (col & 7));
}

// ---------------------------------------------------------------------------
// k_pre: zero cursors | MFMA B-fragment pack + bias (replaces the memset
// launch; runs before k_all so k_all's R1 blocks can use packed[]).
__global__ void k_pre(const void* Wl1, const void* Wr1, const void* Wl2,
                      const void* Wr2, const void* Wl3, const void* Wr3,
                      const void* Wlin1, const void* Wlin2,
                      const void* b1, const void* b2, const void* b3,
                      const void* b4, const void* b5,
                      int* __restrict__ cursor,
                      bf16x8* __restrict__ packed, float* __restrict__ biasf) {
    int b = blockIdx.x, tid = threadIdx.x, lane = tid & 63;
    if (b < CZ_BLOCKS) {
        int i = b * 256 + tid;
        if (i < NNODES / 4 + 1) ((int4*)cursor)[i] = (int4){0, 0, 0, 0};
        return;
    }
    int wf = wave_is_fp32((const unsigned*)Wl1, lane);
    int lb = b - CZ_BLOCKS;              // 0..61
    if (lb >= 59) {
        int t = (lb - 59) * 256 + tid;
        if (t >= 5 * 128) return;
        int which = t >> 7, idx = t & 127;
        const void* srcs[5] = {b1, b2, b3, b4, b5};
        int n = (which == 4) ? NCLS : 128;
        float v = 0.f;
        if (idx < n) v = ldf(srcs[which], wf, idx);
        biasf[t] = v;
        return;
    }
    // frag(kt,nt), lane: elem j = W[kbase + (lane>>4)*8 + j][nt*16 + (lane&15)]
    // layer1 0..63 | layer2 64..127 | layer3 128..191 | lin1 192..223 |
    // lin2 224..235 (KT=4, NT=3, cols >=40 zero-padded)
    int t2 = lb * 256 + tid;
    int frag = t2 >> 6;
    if (frag >= 236) return;
    int q = lane >> 4, l16 = lane & 15;
    const void* W;
    int kbase, n, ldw = 128, nvalid = 128;
    if (frag < 192) {
        int g = frag >> 6, local = frag & 63;
        int kt = local >> 3, nt = local & 7;
        const void* Wl = (g == 0) ? Wl1 : (g == 1) ? Wl2 : Wl3;
        const void* Wr = (g == 0) ? Wr1 : (g == 1) ? Wr2 : Wr3;
        W = (kt < 4) ? Wl : Wr;
        kbase = (kt & 3) * 32;
        n = nt * 16 + l16;
    } else if (frag < 224) {
        int local = frag - 192;
        int kt = local >> 3, nt = local & 7;
        W = Wlin1; kbase = kt * 32; n = nt * 16 + l16;
    } else {
        int local = frag - 224;
        int kt = local / 3, nt = local % 3;
        W = Wlin2; kbase = kt * 32; n = nt * 16 + l16;
        ldw = NCLS; nvalid = NCLS;
    }
    bf16x8 v;
#pragma unroll
    for (int j = 0; j < 8; j++) {
        float e = 0.f;
        if (n < nvalid) e = ldf(W, wf, (kbase + q * 8 + j) * ldw + n);
        v[j] = f2b(e);
    }
    packed[frag * 64 + lane] = v;
}

// ---------------------------------------------------------------------------
// k_all: edge fill (atomic slot claim; critical path) | x->bf16 | R1 =
// x @ Wr1 + bl1 (fp32) — R1 and cvt ride under the fill waves' idle CUs.
__global__ void k_all(const int* __restrict__ e32, const long long* __restrict__ e64,
                      const void* __restrict__ xin,
                      int* __restrict__ cursor, int* __restrict__ edge_src,
                      bf16* __restrict__ xb,
                      const bf16x8* __restrict__ packed,
                      const float* __restrict__ biasf, float* __restrict__ R1) {
    int b = blockIdx.x, tid = threadIdx.x, lane = tid & 63;
    if (b < FILL_BLOCKS) {
        unsigned hw = ((const unsigned*)e32)[2 * lane + 1];
        int is64 = (__ballot(hw != 0u) == 0ull) ? 1 : 0;
        int i0 = b * 512 + tid;
        int i1 = i0 + 256;
        int s0 = 0, d0 = 0, s1 = 0, d1 = 0;
        bool v0 = i0 < NEDGES, v1 = i1 < NEDGES;
        if (v0) { s0 = is64 ? (int)e64[i0] : e32[i0];
                  d0 = is64 ? (int)e64[NEDGES + i0] : e32[NEDGES + i0]; }
        if (v1) { s1 = is64 ? (int)e64[i1] : e32[i1];
                  d1 = is64 ? (int)e64[NEDGES + i1] : e32[NEDGES + i1]; }
        int p0 = 0, p1 = 0;
        if (v0) p0 = atomicAdd(&cursor[d0], 1);
        if (v1) p1 = atomicAdd(&cursor[d1], 1);
        if (v0 && p0 < SLOTS) edge_src[d0 * SLOTS + p0] = s0;
        if (v1 && p1 < SLOTS) edge_src[d1 * SLOTS + p1] = s1;
        return;
    }
    if (b < FILL_BLOCKS + CVT_BLOCKS) {
        int xf = wave_is_fp32((const unsigned*)xin, lane);
        int i = (b - FILL_BLOCKS) * 256 + tid;   // exact: < 50000*128/4
        if (xf) {
            float4 v = ((const float4*)xin)[i];
            bf16x4 o;
            o[0] = f2b(v.x); o[1] = f2b(v.y); o[2] = f2b(v.z); o[3] = f2b(v.w);
            ((bf16x4*)xb)[i] = o;
        } else {
            ((uint2*)xb)[i] = ((const uint2*)xin)[i];
        }
        return;
    }
    // R1 blocks: 16 rows each, wave = 2-nt quarter, K=128 (Wr1 = packed kt 4..7)
    int rb = (b - FILL_BLOCKS - CVT_BLOCKS) * 16;
    int wave = tid >> 6;
    int q = lane >> 4, l16 = lane & 15;
    int xf = wave_is_fp32((const unsigned*)xin, lane);
    bf16x8 a[4];
#pragma unroll
    for (int kt = 0; kt < 4; kt++) {
        if (xf) {
            const float* xp = (const float*)xin +
                              (unsigned)((rb + l16) * FDIM + kt * 32 + q * 8);
            float4 v0 = *(const float4*)xp;
            float4 v1 = *(const float4*)(xp + 4);
            a[kt][0] = f2b(v0.x); a[kt][1] = f2b(v0.y);
            a[kt][2] = f2b(v0.z); a[kt][3] = f2b(v0.w);
            a[kt][4] = f2b(v1.x); a[kt][5] = f2b(v1.y);
            a[kt][6] = f2b(v1.z); a[kt][7] = f2b(v1.w);
        } else {
            a[kt] = *(const bf16x8*)((const bf16*)xin +
                        (unsigned)((rb + l16) * FDIM + kt * 32 + q * 8));
        }
    }
    f32x4 acc[2];
#pragma unroll
    for (int n = 0; n < 2; n++) acc[n] = (f32x4){0.f, 0.f, 0.f, 0.f};
#pragma unroll
    for (int kt = 0; kt < 4; kt++)
#pragma unroll
        for (int n = 0; n < 2; n++)
            acc[n] = __builtin_amdgcn_mfma_f32_16x16x32_bf16(
                a[kt], packed[((kt + 4) * 8 + wave * 2 + n) * 64 + lane],
                acc[n], 0, 0, 0);
#pragma unroll
    for (int n = 0; n < 2; n++) {
        int col = (wave * 2 + n) * 16 + l16;
        float bv = biasf[col];
#pragma unroll
        for (int r = 0; r < 4; r++)
            R1[(unsigned)((rb + q * 4 + r) * FDIM + col)] = acc[n][r] + bv;
    }
}

// ---------------------------------------------------------------------------
// agg4: one wave aggregates 4 nodes in ONE pass; group g (16 lanes) owns
// node rowbase + wave*4 + g's full 128-col row (16 gathers in flight, no
// cross-group reduce). Packed f32x2 accumulate; pad slots clamp + mask.
__device__ __forceinline__ void agg4(const bf16* __restrict__ x,
        const int* __restrict__ deg, const int* __restrict__ es,
        short* __restrict__ lds, int rowbase, int wave, int lane) {
    const int g = lane >> 4, c = lane & 15;
    const int gsel = lane & 48;
    const int node = rowbase + wave * 4 + g;
    const int dg = deg[node];
    int ei = es[node * SLOTS + c];
    if ((unsigned)ei >= NNODES) ei = 0;
    f32x2 acc2[4];
#pragma unroll
    for (int k = 0; k < 4; k++) acc2[k] = (f32x2){0.f, 0.f};
#pragma unroll
    for (int j = 0; j < 16; j++) {
        int idx = __shfl(ei, gsel | j);
        float m = (j < dg) ? 1.f : 0.f;
        f32x2 m2 = (f32x2){m, m};
        u32x4 u = *(const u32x4*)(x + (unsigned)(idx * FDIM + c * 8));
#pragma unroll
        for (int k = 0; k < 4; k++) {
            f32x2 vv = (f32x2){u2f(u[k] << 16), u2f(u[k] & 0xFFFF0000u)};
            acc2[k] += vv * m2;
        }
    }
    if (__ballot(dg > 16) != 0ull) {                 // rare: deg > 16
        for (int jb = 16; jb < SLOTS && __ballot(dg > jb) != 0ull; jb += 16) {
            int ei2 = es[node * SLOTS + jb + c];
            if ((unsigned)ei2 >= NNODES) ei2 = 0;
            for (int j = 0; j < 16; j++) {
                int idx = __shfl(ei2, gsel | j);
                float m = (jb + j < dg) ? 1.f : 0.f;
                f32x2 m2 = (f32x2){m, m};
                u32x4 u = *(const u32x4*)(x + (unsigned)(idx * FDIM + c * 8));
#pragma unroll
                for (int k = 0; k < 4; k++) {
                    f32x2 vv = (f32x2){u2f(u[k] << 16), u2f(u[k] & 0xFFFF0000u)};
                    acc2[k] += vv * m2;
                }
            }
        }
    }
    float inv = (dg > 0) ? 1.f / (float)dg : 0.f;
    bf16x8 o;
#pragma unroll
    for (int k = 0; k < 4; k++) {
        o[2 * k]     = f2b(acc2[k].x * inv);
        o[2 * k + 1] = f2b(acc2[k].y * inv);
    }
    *(bf16x8*)(lds + lidx(wave * 4 + g, c * 8)) = o;
}

// ---------------------------------------------------------------------------
// gemm_q: GEMM over the tile's 16 rows, this wave owning a 2-nt quarter.
// FIRST: K=128 agg-half only + R1 add (bias already in R1); else K=256 with
// rt[] root half and bias. Relu rows written back into LDS for store/head.
template <bool FIRST>
__device__ __forceinline__ void gemm_q(int rowbase, int lane, int wave,
        short* __restrict__ lds, const bf16x8 rt[4],
        const bf16x8* __restrict__ packed, const float* __restrict__ bias,
        const float* __restrict__ R1) {
    const int q = lane >> 4, l16 = lane & 15;
    f32x4 acc[2];
#pragma unroll
    for (int n = 0; n < 2; n++) acc[n] = (f32x4){0.f, 0.f, 0.f, 0.f};
    const int KT = FIRST ? 4 : 8;
#pragma unroll
    for (int kt = 0; kt < KT; kt++) {
        bf16x8 a;
        if (kt < 4)
            a = *(const bf16x8*)(lds + lidx(l16, kt * 32 + q * 8));
        else
            a = rt[kt - 4];
#pragma unroll
        for (int n = 0; n < 2; n++)
            acc[n] = __builtin_amdgcn_mfma_f32_16x16x32_bf16(
                a, packed[(kt * 8 + wave * 2 + n) * 64 + lane], acc[n], 0, 0, 0);
    }
    __syncthreads();                 // all waves' LDS reads complete
#pragma unroll
    for (int n = 0; n < 2; n++) {
        int col = (wave * 2 + n) * 16 + l16;
        float bv = FIRST ? 0.f : bias[col];
#pragma unroll
        for (int r = 0; r < 4; r++) {
            float v = acc[n][r] + bv;
            if (FIRST) v += R1[(unsigned)((rowbase + q * 4 + r) * FDIM + col)];
            lds[lidx(q * 4 + r, col)] = f2b(fmaxf(v, 0.f));
        }
    }
    __syncthreads();                 // write-back visible to all waves
}

// store_q: (wave, group) pair stores row wave*4+g, 16B/lane contiguous.
__device__ __forceinline__ void store_q(int rowbase, int lane, int wave,
        const short* __restrict__ lds, bf16* __restrict__ out) {
    const int g = lane >> 4, c = lane & 15;
    int p = wave * 4 + g;
    bf16x8 v = *(const bf16x8*)(lds + lidx(p, c * 8));
    *(bf16x8*)(out + (unsigned)((rowbase + p) * FDIM + c * 8)) = v;
}

// ---------------------------------------------------------------------------
// head: lin1 (2-nt quarter waves, h3 -> h1) -> barrier -> wave 0: lin2 (40
// cols) + log_softmax -> fp32 out.
__device__ __forceinline__ void head(int rowbase, int lane, int wave,
        const short* __restrict__ h3, short* __restrict__ h1,
        const bf16x8* __restrict__ packed, const float* __restrict__ bias1,
        const float* __restrict__ bias2, float* __restrict__ out) {
    const int q = lane >> 4, l16 = lane & 15;
    f32x4 acc[2];
#pragma unroll
    for (int n = 0; n < 2; n++) acc[n] = (f32x4){0.f, 0.f, 0.f, 0.f};
#pragma unroll
    for (int kt = 0; kt < 4; kt++) {
        bf16x8 a = *(const bf16x8*)(h3 + lidx(l16, kt * 32 + q * 8));
#pragma unroll
        for (int n = 0; n < 2; n++)
            acc[n] = __builtin_amdgcn_mfma_f32_16x16x32_bf16(
                a, packed[(192 + kt * 8 + wave * 2 + n) * 64 + lane], acc[n], 0, 0, 0);
    }
#pragma unroll
    for (int n = 0; n < 2; n++) {
        int col = (wave * 2 + n) * 16 + l16;
        float bv = bias1[col];
#pragma unroll
        for (int r = 0; r < 4; r++)
            h1[lidx(q * 4 + r, col)] = f2b(fmaxf(acc[n][r] + bv, 0.f));
    }
    __syncthreads();
    if (wave != 0) return;
    f32x4 acc2[3];
#pragma unroll
    for (int n = 0; n < 3; n++) acc2[n] = (f32x4){0.f, 0.f, 0.f, 0.f};
#pragma unroll
    for (int kt = 0; kt < 4; kt++) {
        bf16x8 a = *(const bf16x8*)(h1 + lidx(l16, kt * 32 + q * 8));
#pragma unroll
        for (int n = 0; n < 3; n++)
            acc2[n] = __builtin_amdgcn_mfma_f32_16x16x32_bf16(
                a, packed[(224 + kt * 3 + n) * 64 + lane], acc2[n], 0, 0, 0);
    }
    const float NEG = -1e30f;
    bool v2ok = (l16 < 8);
#pragma unroll
    for (int r = 0; r < 4; r++) {
        unsigned row = (unsigned)(rowbase + q * 4 + r);
        float v0 = acc2[0][r] + bias2[l16];
        float v1 = acc2[1][r] + bias2[16 + l16];
        float v2 = v2ok ? (acc2[2][r] + bias2[32 + l16]) : NEG;
        float m = fmaxf(fmaxf(v0, v1), v2);
#pragma unroll
        for (int mk = 1; mk < 16; mk <<= 1) m = fmaxf(m, __shfl_xor(m, mk));
        float sden = expf(v0 - m) + expf(v1 - m) + (v2ok ? expf(v2 - m) : 0.f);
#pragma unroll
        for (int mk = 1; mk < 16; mk <<= 1) sden += __shfl_xor(sden, mk);
        float l = m + logf(sden);
        out[row * NCLS + l16] = v0 - l;
        out[row * NCLS + 16 + l16] = v1 - l;
        if (v2ok) out[row * NCLS + 32 + l16] = v2 - l;
    }
}

// ---------------------------------------------------------------------------
// 4 waves per 16-row tile: wave w aggregates 4 nodes (one pass), then
// computes 2-nt GEMM quarter. 12500 total waves (2x r17) for latency hiding.
template <bool FIRST>
__global__ void __launch_bounds__(256)
k_layer_t(const bf16* __restrict__ src, const int* __restrict__ deg,
          const int* __restrict__ edge_src, const bf16x8* __restrict__ packed,
          const float* __restrict__ bias, const float* __restrict__ R1,
          bf16* __restrict__ out) {
    __shared__ __align__(16) short lds[16 * 128];
    const int lane = threadIdx.x & 63, wave = threadIdx.x >> 6;
    const int rowbase = blockIdx.x * 16;
    const int q = lane >> 4, l16 = lane & 15;
    bf16x8 rt[4];
    if (!FIRST) {
#pragma unroll
        for (int kt = 0; kt < 4; kt++)
            rt[kt] = *(const bf16x8*)(src +
                         (unsigned)((rowbase + l16) * FDIM + kt * 32 + q * 8));
    }
    agg4(src, deg, edge_src, lds, rowbase, wave, lane);
    __syncthreads();
    gemm_q<FIRST>(rowbase, lane, wave, lds, rt, packed, bias, R1);
    store_q(rowbase, lane, wave, lds, out);
}

__global__ void __launch_bounds__(256)
k_layer3head(const bf16* __restrict__ src, const int* __restrict__ deg,
             const int* __restrict__ edge_src, const bf16x8* __restrict__ packed,
             const float* __restrict__ biasf, float* __restrict__ out) {
    __shared__ __align__(16) short h3[16 * 128];
    __shared__ __align__(16) short h1[16 * 128];
    const int lane = threadIdx.x & 63, wave = threadIdx.x >> 6;
    const int rowbase = blockIdx.x * 16;
    const int q = lane >> 4, l16 = lane & 15;
    bf16x8 rt[4];
#pragma unroll
    for (int kt = 0; kt < 4; kt++)
        rt[kt] = *(const bf16x8*)(src +
                     (unsigned)((rowbase + l16) * FDIM + kt * 32 + q * 8));
    agg4(src, deg, edge_src, h3, rowbase, wave, lane);
    __syncthreads();
    gemm_q<false>(rowbase, lane, wave, h3, rt, packed + 128 * 64,
                  biasf + 256, nullptr);
    head(rowbase, lane, wave, h3, h1, packed, biasf + 384, biasf + 512, out);
}

// ---------------------------------------------------------------------------
extern "C" void kernel_launch(void* const* d_in, const int* in_sizes, int n_in,
                              void* d_out, int out_size, void* d_ws, size_t ws_size,
                              hipStream_t stream) {
    char* ws = (char*)d_ws;
    size_t off = 0;
    auto take = [&](size_t bytes) {
        void* pp = ws + off;
        off = (off + bytes + 255) & ~(size_t)255;
        return pp;
    };
    const int* e32 = (const int*)d_in[1];
    const long long* e64 = (const long long*)d_in[1];
    int* cursor    = (int*)take((NNODES + 16) * 4);
    int* edge_src  = (int*)take((size_t)NNODES * SLOTS * 4);   // uninit pads OK
    bf16x8* packed = (bf16x8*)take(236 * 64 * 16);
    float* biasf   = (float*)take(5 * 128 * 4);
    float* R1      = (float*)take((size_t)NNODES * FDIM * 4);
    bf16* xb       = (bf16*)take((size_t)NNODES * FDIM * 2);
    bf16* bufA     = (bf16*)take((size_t)NNODES * FDIM * 2);
    float* outp    = (float*)d_out;
    bf16* bufB     = xb;    // x dead after layer 1

    k_pre<<<PRE_TOTAL, 256, 0, stream>>>(
        d_in[2], d_in[4], d_in[5], d_in[7], d_in[8], d_in[10], d_in[11],
        d_in[13], d_in[3], d_in[6], d_in[9], d_in[12], d_in[14],
        cursor, packed, biasf);
    k_all<<<ALL_TOTAL, 256, 0, stream>>>(
        e32, e64, d_in[0], cursor, edge_src, xb, packed, biasf, R1);

    // layer 1: xb -> bufA (root half via R1)
    k_layer_t<true><<<NT16, 256, 0, stream>>>(xb, cursor, edge_src, packed,
                                              biasf, R1, bufA);
    // layer 2: bufA -> bufB (aliases xb)
    k_layer_t<false><<<NT16, 256, 0, stream>>>(bufA, cursor, edge_src,
                                               packed + 64 * 64, biasf + 128,
                                               nullptr, bufB);
    // layer 3 + head: bufB -> out
    k_layer3head<<<NT16, 256, 0, stream>>>(bufB, cursor, edge_src,
                                           packed, biasf, outp);
}

// Round 19
// 227.980 us; speedup vs baseline: 1.0688x; 1.0688x over previous
//
#include <hip/hip_runtime.h>
#include <hip/hip_bf16.h>
#include <math.h>

#define NNODES 50000
#define NEDGES 600000
#define FDIM   128
#define NCLS   40
#define SLOTS  64                        // static CSR slots per node (start = node*64)
#define FILL_BLOCKS 2344                 // 1 edge/thread (r14-measured best)
#define CVT_BLOCKS 6250                  // 50000*128/4/256 exact
#define PACK_BLOCKS 62
#define ALL_TOTAL (FILL_BLOCKS + CVT_BLOCKS + PACK_BLOCKS)
#define NT16 (NNODES / 16)               // 3125 two-wave tiles of 16 rows (exact)

typedef __hip_bfloat16 bf16;
typedef short bf16x8 __attribute__((ext_vector_type(8)));
typedef short bf16x4 __attribute__((ext_vector_type(4)));
typedef float f32x4  __attribute__((ext_vector_type(4)));
typedef float f32x2  __attribute__((ext_vector_type(2)));
typedef unsigned u32x4 __attribute__((ext_vector_type(4)));

__device__ __forceinline__ float u2f(unsigned u) {
    union { unsigned i; float f; } cv;
    cv.i = u;
    return cv.f;
}
__device__ __forceinline__ short f2b(float f) {
    bf16 h = __float2bfloat16(f);
    return *(const short*)&h;
}
__device__ __forceinline__ float ldf(const void* p, int fp32, int idx) {
    return fp32 ? ((const float*)p)[idx]
                : __bfloat162float(((const bf16*)p)[idx]);
}
// Per-wave float-dtype detection from 64 samples of the array's first words.
__device__ __forceinline__ int wave_is_fp32(const unsigned* p, int lane) {
    unsigned w = p[lane];
    unsigned e = (w >> 7) & 0xFFu;
    int inr = (e >= 100u && e <= 140u) ? 1 : 0;
    return (int)__popcll(__ballot(inr)) < 32;
}
// LDS addressing: flat 128-short rows, 8-short chunks XOR-swizzled by row&15.
// [verified r9-r18: SQ_LDS_BANK_CONFLICT = 0]
__device__ __forceinline__ int lidx(int row, int col) {
    return row * 128 + ((((col >> 3) ^ (row & 15)) << 3) | (col & 7));
}

// ---------------------------------------------------------------------------
// k_all: edge fill (1 edge/thread, atomic slot claim; cursor ends as deg)
// | x->bf16 | weight pack + bias. Fill blocks first (critical path).
__global__ void k_all(const int* __restrict__ e32, const long long* __restrict__ e64,
                      const void* __restrict__ xin,
                      const void* Wl1, const void* Wr1, const void* Wl2,
                      const void* Wr2, const void* Wl3, const void* Wr3,
                      const void* Wlin1, const void* Wlin2,
                      const void* b1, const void* b2, const void* b3,
                      const void* b4, const void* b5,
                      int* __restrict__ cursor, int* __restrict__ edge_src,
                      bf16* __restrict__ xb,
                      bf16x8* __restrict__ packed, float* __restrict__ biasf) {
    int b = blockIdx.x, tid = threadIdx.x, lane = tid & 63;
    if (b < FILL_BLOCKS) {
        unsigned hw = ((const unsigned*)e32)[2 * lane + 1];
        int is64 = (__ballot(hw != 0u) == 0ull) ? 1 : 0;
        int i = b * 256 + tid;
        if (i < NEDGES) {
            int srcn = is64 ? (int)e64[i] : e32[i];
            int dstn = is64 ? (int)e64[NEDGES + i] : e32[NEDGES + i];
            int pos = atomicAdd(&cursor[dstn], 1);
            if (pos < SLOTS) edge_src[dstn * SLOTS + pos] = srcn;
        }
        return;
    }
    if (b < FILL_BLOCKS + CVT_BLOCKS) {
        int xf = wave_is_fp32((const unsigned*)xin, lane);
        int i = (b - FILL_BLOCKS) * 256 + tid;   // exact: < 50000*128/4
        if (xf) {
            float4 v = ((const float4*)xin)[i];
            bf16x4 o;
            o[0] = f2b(v.x); o[1] = f2b(v.y); o[2] = f2b(v.z); o[3] = f2b(v.w);
            ((bf16x4*)xb)[i] = o;
        } else {
            ((uint2*)xb)[i] = ((const uint2*)xin)[i];
        }
        return;
    }
    int wf = wave_is_fp32((const unsigned*)Wl1, lane);
    int lb = b - FILL_BLOCKS - CVT_BLOCKS;       // 0..61
    if (lb >= 59) {
        int t = (lb - 59) * 256 + tid;
        if (t >= 5 * 128) return;
        int which = t >> 7, idx = t & 127;
        const void* srcs[5] = {b1, b2, b3, b4, b5};
        int n = (which == 4) ? NCLS : 128;
        float v = 0.f;
        if (idx < n) v = ldf(srcs[which], wf, idx);
        biasf[t] = v;
        return;
    }
    // MFMA B-fragment pack: frag(kt,nt), lane: elem j =
    //   W[kbase + (lane>>4)*8 + j][nt*16 + (lane&15)]
    // layer1 0..63 | layer2 64..127 | layer3 128..191 | lin1 192..223 |
    // lin2 224..235 (KT=4, NT=3, cols >=40 zero-padded)
    int t2 = lb * 256 + tid;
    int frag = t2 >> 6;
    if (frag >= 236) return;
    int q = lane >> 4, l16 = lane & 15;
    const void* W;
    int kbase, n, ldw = 128, nvalid = 128;
    if (frag < 192) {
        int g = frag >> 6, local = frag & 63;
        int kt = local >> 3, nt = local & 7;
        const void* Wl = (g == 0) ? Wl1 : (g == 1) ? Wl2 : Wl3;
        const void* Wr = (g == 0) ? Wr1 : (g == 1) ? Wr2 : Wr3;
        W = (kt < 4) ? Wl : Wr;
        kbase = (kt & 3) * 32;
        n = nt * 16 + l16;
    } else if (frag < 224) {
        int local = frag - 192;
        int kt = local >> 3, nt = local & 7;
        W = Wlin1; kbase = kt * 32; n = nt * 16 + l16;
    } else {
        int local = frag - 224;
        int kt = local / 3, nt = local % 3;
        W = Wlin2; kbase = kt * 32; n = nt * 16 + l16;
        ldw = NCLS; nvalid = NCLS;
    }
    bf16x8 v;
#pragma unroll
    for (int j = 0; j < 8; j++) {
        float e = 0.f;
        if (n < nvalid) e = ldf(W, wf, (kbase + q * 8 + j) * ldw + n);
        v[j] = f2b(e);
    }
    packed[frag * 64 + lane] = v;
}

// ---------------------------------------------------------------------------
// agg8: one wave aggregates 8 nodes in 2 passes; group g (16 lanes) owns one
// node's full 128-col row per pass (16 gathers in flight, no cross-group
// reduce). Metadata hoisted; packed f32x2 accumulate; pad slots clamp+mask.
__device__ __forceinline__ void agg8(const bf16* __restrict__ x,
        const int* __restrict__ deg, const int* __restrict__ es,
        short* __restrict__ lds, int node00, int wave, int lane) {
    const int g = lane >> 4, c = lane & 15;
    const int gsel = lane & 48;
    const int nbase = node00 + wave * 8;
    int dgp[2], eip[2];
#pragma unroll
    for (int p = 0; p < 2; p++) dgp[p] = deg[nbase + p * 4 + g];
#pragma unroll
    for (int p = 0; p < 2; p++) {
        int ei = es[(nbase + p * 4 + g) * SLOTS + c];
        eip[p] = ((unsigned)ei >= NNODES) ? 0 : ei;
    }
#pragma unroll
    for (int p = 0; p < 2; p++) {
        const int dg = dgp[p];
        f32x2 acc2[4];
#pragma unroll
        for (int k = 0; k < 4; k++) acc2[k] = (f32x2){0.f, 0.f};
#pragma unroll
        for (int j = 0; j < 16; j++) {
            int idx = __shfl(eip[p], gsel | j);
            float m = (j < dg) ? 1.f : 0.f;
            f32x2 m2 = (f32x2){m, m};
            u32x4 u = *(const u32x4*)(x + (unsigned)(idx * FDIM + c * 8));
#pragma unroll
            for (int k = 0; k < 4; k++) {
                f32x2 vv = (f32x2){u2f(u[k] << 16), u2f(u[k] & 0xFFFF0000u)};
                acc2[k] += vv * m2;
            }
        }
        if (__ballot(dg > 16) != 0ull) {             // rare: deg > 16
            for (int jb = 16; jb < SLOTS && __ballot(dg > jb) != 0ull; jb += 16) {
                int ei2 = es[(nbase + p * 4 + g) * SLOTS + jb + c];
                if ((unsigned)ei2 >= NNODES) ei2 = 0;
                for (int j = 0; j < 16; j++) {
                    int idx = __shfl(ei2, gsel | j);
                    float m = (jb + j < dg) ? 1.f : 0.f;
                    f32x2 m2 = (f32x2){m, m};
                    u32x4 u = *(const u32x4*)(x + (unsigned)(idx * FDIM + c * 8));
#pragma unroll
                    for (int k = 0; k < 4; k++) {
                        f32x2 vv = (f32x2){u2f(u[k] << 16), u2f(u[k] & 0xFFFF0000u)};
                        acc2[k] += vv * m2;
                    }
                }
            }
        }
        float inv = (dg > 0) ? 1.f / (float)dg : 0.f;
        bf16x8 o;
#pragma unroll
        for (int k = 0; k < 4; k++) {
            o[2 * k]     = f2b(acc2[k].x * inv);
            o[2 * k + 1] = f2b(acc2[k].y * inv);
        }
        *(bf16x8*)(lds + lidx(wave * 8 + p * 4 + g, c * 8)) = o;
    }
}

// ---------------------------------------------------------------------------
// gemm_half: K=256 GEMM over the tile's 16 rows, this wave owning col half
// `wave` (4 nt). Root half from rt[] preloaded at entry. Caller barriers.
__device__ __forceinline__ void gemm_half(int lane, int wave,
        short* __restrict__ lds, const bf16x8 rt[4],
        const bf16x8* __restrict__ packed, const float* __restrict__ bias) {
    const int q = lane >> 4, l16 = lane & 15;
    f32x4 acc[4];
#pragma unroll
    for (int n = 0; n < 4; n++) acc[n] = (f32x4){0.f, 0.f, 0.f, 0.f};
#pragma unroll
    for (int kt = 0; kt < 8; kt++) {
        bf16x8 a;
        if (kt < 4)
            a = *(const bf16x8*)(lds + lidx(l16, kt * 32 + q * 8));
        else
            a = rt[kt - 4];
#pragma unroll
        for (int n = 0; n < 4; n++)
            acc[n] = __builtin_amdgcn_mfma_f32_16x16x32_bf16(
                a, packed[(kt * 8 + wave * 4 + n) * 64 + lane], acc[n], 0, 0, 0);
    }
    __syncthreads();                 // both waves' LDS reads complete
#pragma unroll
    for (int n = 0; n < 4; n++) {
        int col = (wave * 4 + n) * 16 + l16;
        float bv = bias[col];
#pragma unroll
        for (int r = 0; r < 4; r++)
            lds[lidx(q * 4 + r, col)] = f2b(fmaxf(acc[n][r] + bv, 0.f));
    }
    __syncthreads();                 // write-back visible to both waves
}

// store_half: wave w stores rows w*8..w*8+7, 1KB-contiguous 16B chunks.
__device__ __forceinline__ void store_half(int rowbase, int lane, int wave,
        const short* __restrict__ lds, bf16* __restrict__ out) {
    const int g = lane >> 4, c = lane & 15;
#pragma unroll
    for (int pp = 0; pp < 2; pp++) {
        int p = wave * 2 + pp;
        bf16x8 v = *(const bf16x8*)(lds + lidx(p * 4 + g, c * 8));
        *(bf16x8*)(out + (unsigned)((rowbase + p * 4 + g) * FDIM + c * 8)) = v;
    }
}

// ---------------------------------------------------------------------------
// head: lin1 (col-half waves, h3 -> h1) -> barrier -> wave 0: lin2 (40
// cols) + log_softmax -> fp32 out.
__device__ __forceinline__ void head(int rowbase, int lane, int wave,
        const short* __restrict__ h3, short* __restrict__ h1,
        const bf16x8* __restrict__ packed, const float* __restrict__ bias1,
        const float* __restrict__ bias2, float* __restrict__ out) {
    const int q = lane >> 4, l16 = lane & 15;
    f32x4 acc[4];
#pragma unroll
    for (int n = 0; n < 4; n++) acc[n] = (f32x4){0.f, 0.f, 0.f, 0.f};
#pragma unroll
    for (int kt = 0; kt < 4; kt++) {
        bf16x8 a = *(const bf16x8*)(h3 + lidx(l16, kt * 32 + q * 8));
#pragma unroll
        for (int n = 0; n < 4; n++)
            acc[n] = __builtin_amdgcn_mfma_f32_16x16x32_bf16(
                a, packed[(192 + kt * 8 + wave * 4 + n) * 64 + lane], acc[n], 0, 0, 0);
    }
#pragma unroll
    for (int n = 0; n < 4; n++) {
        int col = (wave * 4 + n) * 16 + l16;
        float bv = bias1[col];
#pragma unroll
        for (int r = 0; r < 4; r++)
            h1[lidx(q * 4 + r, col)] = f2b(fmaxf(acc[n][r] + bv, 0.f));
    }
    __syncthreads();
    if (wave != 0) return;
    f32x4 acc2[3];
#pragma unroll
    for (int n = 0; n < 3; n++) acc2[n] = (f32x4){0.f, 0.f, 0.f, 0.f};
#pragma unroll
    for (int kt = 0; kt < 4; kt++) {
        bf16x8 a = *(const bf16x8*)(h1 + lidx(l16, kt * 32 + q * 8));
#pragma unroll
        for (int n = 0; n < 3; n++)
            acc2[n] = __builtin_amdgcn_mfma_f32_16x16x32_bf16(
                a, packed[(224 + kt * 3 + n) * 64 + lane], acc2[n], 0, 0, 0);
    }
    const float NEG = -1e30f;
    bool v2ok = (l16 < 8);
#pragma unroll
    for (int r = 0; r < 4; r++) {
        unsigned row = (unsigned)(rowbase + q * 4 + r);
        float v0 = acc2[0][r] + bias2[l16];
        float v1 = acc2[1][r] + bias2[16 + l16];
        float v2 = v2ok ? (acc2[2][r] + bias2[32 + l16]) : NEG;
        float m = fmaxf(fmaxf(v0, v1), v2);
#pragma unroll
        for (int mk = 1; mk < 16; mk <<= 1) m = fmaxf(m, __shfl_xor(m, mk));
        float sden = expf(v0 - m) + expf(v1 - m) + (v2ok ? expf(v2 - m) : 0.f);
#pragma unroll
        for (int mk = 1; mk < 16; mk <<= 1) sden += __shfl_xor(sden, mk);
        float l = m + logf(sden);
        out[row * NCLS + l16] = v0 - l;
        out[row * NCLS + 16 + l16] = v1 - l;
        if (v2ok) out[row * NCLS + 32 + l16] = v2 - l;
    }
}

// ---------------------------------------------------------------------------
// 2 waves per 16-row tile: wave w aggregates 8 nodes, then computes col
// half w of the GEMM. 6250 total waves for latency hiding (r17 optimum).
__global__ void __launch_bounds__(128)
k_layer(const bf16* __restrict__ src, const int* __restrict__ deg,
        const int* __restrict__ edge_src, const bf16x8* __restrict__ packed,
        const float* __restrict__ bias, bf16* __restrict__ out) {
    __shared__ __align__(16) short lds[16 * 128];
    const int lane = threadIdx.x & 63, wave = threadIdx.x >> 6;
    const int rowbase = blockIdx.x * 16;
    const int q = lane >> 4, l16 = lane & 15;
    bf16x8 rt[4];
#pragma unroll
    for (int kt = 0; kt < 4; kt++)
        rt[kt] = *(const bf16x8*)(src +
                     (unsigned)((rowbase + l16) * FDIM + kt * 32 + q * 8));
    agg8(src, deg, edge_src, lds, rowbase, wave, lane);
    __syncthreads();
    gemm_half(lane, wave, lds, rt, packed, bias);
    store_half(rowbase, lane, wave, lds, out);
}

__global__ void __launch_bounds__(128)
k_layer3head(const bf16* __restrict__ src, const int* __restrict__ deg,
             const int* __restrict__ edge_src, const bf16x8* __restrict__ packed,
             const float* __restrict__ biasf, float* __restrict__ out) {
    __shared__ __align__(16) short h3[16 * 128];
    __shared__ __align__(16) short h1[16 * 128];
    const int lane = threadIdx.x & 63, wave = threadIdx.x >> 6;
    const int rowbase = blockIdx.x * 16;
    const int q = lane >> 4, l16 = lane & 15;
    bf16x8 rt[4];
#pragma unroll
    for (int kt = 0; kt < 4; kt++)
        rt[kt] = *(const bf16x8*)(src +
                     (unsigned)((rowbase + l16) * FDIM + kt * 32 + q * 8));
    agg8(src, deg, edge_src, h3, rowbase, wave, lane);
    __syncthreads();
    gemm_half(lane, wave, h3, rt, packed + 128 * 64, biasf + 256);
    head(rowbase, lane, wave, h3, h1, packed, biasf + 384, biasf + 512, out);
}

// ---------------------------------------------------------------------------
extern "C" void kernel_launch(void* const* d_in, const int* in_sizes, int n_in,
                              void* d_out, int out_size, void* d_ws, size_t ws_size,
                              hipStream_t stream) {
    char* ws = (char*)d_ws;
    size_t off = 0;
    auto take = [&](size_t bytes) {
        void* pp = ws + off;
        off = (off + bytes + 255) & ~(size_t)255;
        return pp;
    };
    const int* e32 = (const int*)d_in[1];
    const long long* e64 = (const long long*)d_in[1];
    int* cursor    = (int*)take(NNODES * 4);
    int* edge_src  = (int*)take((size_t)NNODES * SLOTS * 4);   // uninit pads OK
    bf16x8* packed = (bf16x8*)take(236 * 64 * 16);
    float* biasf   = (float*)take(5 * 128 * 4);
    bf16* xb       = (bf16*)take((size_t)NNODES * FDIM * 2);
    bf16* bufA     = (bf16*)take((size_t)NNODES * FDIM * 2);
    float* outp    = (float*)d_out;
    bf16* bufB     = xb;    // x dead after layer 1

    hipMemsetAsync(cursor, 0, NNODES * 4, stream);
    k_all<<<ALL_TOTAL, 256, 0, stream>>>(
        e32, e64, d_in[0], d_in[2], d_in[4], d_in[5], d_in[7], d_in[8],
        d_in[10], d_in[11], d_in[13], d_in[3], d_in[6], d_in[9], d_in[12],
        d_in[14], cursor, edge_src, xb, packed, biasf);

    // layer 1: xb -> bufA
    k_layer<<<NT16, 128, 0, stream>>>(xb, cursor, edge_src, packed, biasf, bufA);
    // layer 2: bufA -> bufB (aliases xb)
    k_layer<<<NT16, 128, 0, stream>>>(bufA, cursor, edge_src,
                                      packed + 64 * 64, biasf + 128, bufB);
    // layer 3 + head: bufB -> out
    k_layer3head<<<NT16, 128, 0, stream>>>(bufB, cursor, edge_src,
                                           packed, biasf, outp);
}